// Round 6
// baseline (288.471 us; speedup 1.0000x reference)
//
#include <hip/hip_runtime.h>

typedef unsigned short ushort_t;
typedef short s16x8 __attribute__((ext_vector_type(8)));
typedef float f32x4 __attribute__((ext_vector_type(4)));

#define MFMA16(a, b, c) __builtin_amdgcn_mfma_f32_16x16x32_bf16((a), (b), (c), 0, 0, 0)

// ---- sizes ----
#define BATCH 16
#define N1 1024
#define C1 256
#define N2 256
#define N3 64
// proj block counts: f3 16-row, f2 16-row, f1 64-row
#define PB3 64
#define PB2 256
#define PB1 256
// LDS transpose row stride (ushorts): 72*2=144 B (16B-aligned, ~2-way conflict = free)
#define TSTRIDE 72
// attpv partial-sum LDS row stride (floats): 260 -> 2-way conflict only
#define PSS 260

// float -> bf16 bits, round-to-nearest-even
static __device__ __forceinline__ ushort_t f2b(float f) {
    unsigned int u = __builtin_bit_cast(unsigned int, f);
    unsigned int r = (u + 0x7fffu + ((u >> 16) & 1u)) >> 16;
    return (ushort_t)r;
}
static __device__ __forceinline__ float b2f(ushort_t b) {
    unsigned int u = ((unsigned int)b) << 16;
    return __builtin_bit_cast(float, u);
}

static __device__ __forceinline__ s16x8 cvt8(const float* p) {
    f32x4 lo = *reinterpret_cast<const f32x4*>(p);
    f32x4 hi = *reinterpret_cast<const f32x4*>(p + 4);
    s16x8 r;
#pragma unroll
    for (int i = 0; i < 4; ++i) {
        r[i]     = (short)f2b(lo[i]);
        r[i + 4] = (short)f2b(hi[i]);
    }
    return r;
}

// ---- merged transpose+convert of weights: wt[d][k] = bf16(w[k][d]) ----
__global__ void k_wt(const float* __restrict__ w1, const float* __restrict__ w2,
                     const float* __restrict__ w3,
                     ushort_t* __restrict__ w1t, ushort_t* __restrict__ w2t,
                     ushort_t* __restrict__ w3t) {
    int i = blockIdx.x * 256 + threadIdx.x;
    if (i < 65536) {
        int d = i >> 8, k = i & 255;
        w1t[i] = f2b(w1[k * 256 + d]);
    } else if (i < 65536 + 131072) {
        int j = i - 65536;
        int d = j >> 9, k = j & 511;
        w2t[j] = f2b(w2[k * 256 + d]);
    } else if (i < 65536 + 131072 + 262144) {
        int j = i - 65536 - 131072;
        int d = j >> 10, k = j & 1023;
        w3t[j] = f2b(w3[k * 256 + d]);
    }
}

// 16-row x 256-col projection tile, compile-time K (unrollable / pipelined)
template <int K>
static __device__ __forceinline__ void proj16(
    const float* __restrict__ A, const ushort_t* __restrict__ wt,
    const float* __restrict__ bias, ushort_t* __restrict__ xb,
    int tile, int w, int lr, int lk)
{
    int rowBase = tile * 16;
    const float* arow = A + (size_t)(rowBase + lr) * K + lk;
    f32x4 acc[4] = {};
#pragma unroll 4
    for (int kk = 0; kk < K; kk += 32) {
        s16x8 af = cvt8(arow + kk);
#pragma unroll
        for (int t = 0; t < 4; ++t) {
            const ushort_t* bp = wt + (size_t)(w * 64 + t * 16 + lr) * K + kk + lk;
            acc[t] = MFMA16(af, *reinterpret_cast<const s16x8*>(bp), acc[t]);
        }
    }
    int r0 = rowBase + (lk >> 3) * 4;
#pragma unroll
    for (int t = 0; t < 4; ++t) {
        int c = w * 64 + t * 16 + lr;
        float bs = bias[c];
#pragma unroll
        for (int j = 0; j < 4; ++j)
            xb[(size_t)(r0 + j) * 256 + c] = f2b(acc[t][j] + bs);
    }
}

// ---- merged projection GEMM ----
// f3: 16-row blocks [0,PB3); f2: [PB3,PB3+PB2); f1: 64-row blocks with LDS transpose.
__global__ __launch_bounds__(256) void k_proj(
    const float* __restrict__ f1, const float* __restrict__ f2,
    const float* __restrict__ f3,
    const ushort_t* __restrict__ w1t, const ushort_t* __restrict__ w2t,
    const ushort_t* __restrict__ w3t,
    const float* __restrict__ b1, const float* __restrict__ b2,
    const float* __restrict__ b3,
    ushort_t* __restrict__ x1b, ushort_t* __restrict__ x1t,
    ushort_t* __restrict__ x2b, ushort_t* __restrict__ x3b)
{
    __shared__ ushort_t sT[256 * TSTRIDE];   // 36.9 KB (f1 path only)

    int bid = blockIdx.x;
    int w = threadIdx.x >> 6, l = threadIdx.x & 63;
    int lr = l & 15, g = l >> 4, lk = g * 8;

    if (bid < PB3) {
        proj16<1024>(f3, w3t, b3, x3b, bid, w, lr, lk);
    } else if (bid < PB3 + PB2) {
        proj16<512>(f2, w2t, b2, x2b, bid - PB3, w, lr, lk);
    } else {
        // f1: 64 rows x 256 cols; wave w covers rows w*16..+16, all 256 cols
        int tile = bid - PB3 - PB2;
        int rowBase = tile * 64;
        const float* arow = f1 + (size_t)(rowBase + w * 16 + lr) * 256 + lk;

        f32x4 acc[16] = {};
#pragma unroll 2
        for (int kk = 0; kk < 256; kk += 32) {
            s16x8 af = cvt8(arow + kk);
#pragma unroll
            for (int t = 0; t < 16; ++t) {
                const ushort_t* bp = w1t + (size_t)(t * 16 + lr) * 256 + kk + lk;
                acc[t] = MFMA16(af, *reinterpret_cast<const s16x8*>(bp), acc[t]);
            }
        }
        int rl0 = w * 16 + g * 4;
#pragma unroll
        for (int t = 0; t < 16; ++t) {
            int c = t * 16 + lr;
            float bs = b1[c];
#pragma unroll
            for (int j = 0; j < 4; ++j) {
                float v = acc[t][j] + bs;
                ushort_t bits = f2b(v);
                x1b[(size_t)(rowBase + rl0 + j) * 256 + c] = bits;
                sT[c * TSTRIDE + rl0 + j] = bits;
            }
        }
        __syncthreads();
        // coalesced x1t write: 4 iters, thread covers row c=it*64+(t>>2), 32B chunk q=t&3
        int b = rowBase >> 10, mBase = rowBase & 1023;
        int q = threadIdx.x & 3;
#pragma unroll
        for (int it = 0; it < 4; ++it) {
            int c = it * 64 + (threadIdx.x >> 2);
            const uint4* src = reinterpret_cast<const uint4*>(&sT[c * TSTRIDE + q * 16]);
            uint4* dst = reinterpret_cast<uint4*>(&x1t[(((size_t)b * 256 + c) << 10) + mBase + q * 16]);
            dst[0] = src[0];
            dst[1] = src[1];
        }
    }
}

// ---- merged Gram matrices ----
__global__ __launch_bounds__(256) void k_xxt(
    const ushort_t* __restrict__ x2b, const ushort_t* __restrict__ x3b,
    float* __restrict__ att2, float* __restrict__ att3)
{
    int bid = blockIdx.x;
    const ushort_t* x; float* att; int n, b, bx, by;
    if (bid < 16) { x = x3b; att = att3; n = 64; b = bid; bx = 0; by = 0; }
    else {
        int j = bid - 16;
        x = x2b; att = att2; n = 256;
        b = j >> 4; bx = (j & 15) & 3; by = (j & 15) >> 2;
    }
    int w = threadIdx.x >> 6, l = threadIdx.x & 63;
    int lr = l & 15, lk = (l >> 4) * 8;
    int rowBase = bx * 64 + (w >> 1) * 32;
    int colBase = by * 64 + (w & 1) * 32;
    const ushort_t* xb = x + (size_t)b * n * 256;

    f32x4 acc[2][2] = {};
#pragma unroll 2
    for (int kk = 0; kk < 256; kk += 32) {
        s16x8 a[2], bb[2];
#pragma unroll
        for (int i = 0; i < 2; ++i)
            a[i] = *reinterpret_cast<const s16x8*>(xb + (size_t)(rowBase + i * 16 + lr) * 256 + kk + lk);
#pragma unroll
        for (int j = 0; j < 2; ++j)
            bb[j] = *reinterpret_cast<const s16x8*>(xb + (size_t)(colBase + j * 16 + lr) * 256 + kk + lk);
#pragma unroll
        for (int i = 0; i < 2; ++i)
#pragma unroll
            for (int j = 0; j < 2; ++j)
                acc[i][j] = MFMA16(a[i], bb[j], acc[i][j]);
    }
    float* ab = att + (size_t)b * n * n;
#pragma unroll
    for (int i = 0; i < 2; ++i)
#pragma unroll
        for (int j = 0; j < 2; ++j)
#pragma unroll
            for (int q = 0; q < 4; ++q) {
                int r = rowBase + i * 16 + (l >> 4) * 4 + q;
                int c = colBase + j * 16 + lr;
                ab[(size_t)r * n + c] = acc[i][j][q];
            }
}

// ---- fused attention, split-mm version ----
// block = 16 Q-rows, 4 waves; wave w covers mm in [w*256,(w+1)*256); LDS pairwise reduce.
// 1D grid of 1024 decoded so linear%8 == batch%8 (all blocks of a batch on one XCD).
__global__ __launch_bounds__(256) void k_attpv(
    const ushort_t* __restrict__ x1b, const ushort_t* __restrict__ x1t,
    const float* __restrict__ att2, const float* __restrict__ att3,
    const float* __restrict__ a1p, const float* __restrict__ a2p,
    const float* __restrict__ a3p, float* __restrict__ out)
{
    __shared__ float ps[2][16][PSS];   // 33.3 KB

    int i = blockIdx.x;
    int b = (i & 7) | ((i >> 9) << 3);   // batch: linear%8 == batch%8
    int qtile = (i >> 3) & 63;
    int w = threadIdx.x >> 6, l = threadIdx.x & 63;
    int idx = l & 15, g = l >> 4;
    int rowBase = qtile * 16;
    const ushort_t* X = x1b + (size_t)b * N1 * C1;   // [1024][256]
    const ushort_t* V = x1t + (size_t)b * C1 * N1;   // [256][1024]

    // this block's 16 Q-row fragments (same for all waves; L1-cached)
    s16x8 rf[8];
    const ushort_t* rowp = X + (size_t)(rowBase + idx) * 256 + g * 8;
#pragma unroll
    for (int ks = 0; ks < 8; ++ks) rf[ks] = *reinterpret_cast<const s16x8*>(rowp + ks * 32);

    // per-lane row-bilinear constants (nn fixed per lane)
    int nn = rowBase + idx;
    const float* A2 = att2 + (size_t)b * N2 * N2;
    const float* A3 = att3 + (size_t)b * N3 * N3;
    int r2l = nn >> 2; int r2h = min(r2l + 1, N2 - 1); float fr2 = (float)(nn & 3) * 0.25f;
    const float* A2lo = A2 + r2l * N2; const float* A2hi = A2 + r2h * N2;
    int r3l = nn >> 4; int r3h = min(r3l + 1, N3 - 1); float fr3 = (float)(nn & 15) * 0.0625f;
    const float* A3lo = A3 + r3l * N3; const float* A3hi = A3 + r3h * N3;
    float a1 = *a1p, a2 = *a2p, a3 = *a3p;

    f32x4 acc[16] = {};   // partial out[16 rows][256 cols] over this wave's mm range

    int mmBeg = w * 256, mmEnd = mmBeg + 256;
    for (int mm0 = mmBeg; mm0 < mmEnd; mm0 += 32) {
        f32x4 t0 = {}, t1 = {};
        const ushort_t* c0 = X + (size_t)(mm0 + idx) * 256 + g * 8;
        const ushort_t* c1 = c0 + 16 * 256;
#pragma unroll
        for (int ks = 0; ks < 8; ++ks) {
            s16x8 ca = *reinterpret_cast<const s16x8*>(c0 + ks * 32);
            s16x8 cb = *reinterpret_cast<const s16x8*>(c1 + ks * 32);
            t0 = MFMA16(ca, rf[ks], t0);
            t1 = MFMA16(cb, rf[ks], t1);
        }
        // hoisted bilinear taps
        int c2a = (mm0 >> 2) + g;        int c2ah = min(c2a + 1, N2 - 1);
        int c2b = ((mm0 + 16) >> 2) + g; int c2bh = min(c2b + 1, N2 - 1);
        float p00 = A2lo[c2a], p01 = A2lo[c2ah], p10 = A2hi[c2a], p11 = A2hi[c2ah];
        float q00 = A2lo[c2b], q01 = A2lo[c2bh], q10 = A2hi[c2b], q11 = A2hi[c2bh];
        int c3a = mm0 >> 4; int c3ah = min(c3a + 1, N3 - 1); int c3bh = min(c3a + 2, N3 - 1);
        float s00 = A3lo[c3a], s01 = A3lo[c3ah], s10 = A3hi[c3a], s11 = A3hi[c3ah];
        float u01 = A3lo[c3bh], u11 = A3hi[c3bh];
#pragma unroll
        for (int r = 0; r < 4; ++r) {
            float fc2 = (float)r * 0.25f;
            float fc3 = (float)(g * 4 + r) * 0.0625f;
            float e0 = p00 + fc2 * (p01 - p00), e1 = p10 + fc2 * (p11 - p10);
            float v2 = e0 + fr2 * (e1 - e0);
            float f0 = s00 + fc3 * (s01 - s00), f1v = s10 + fc3 * (s11 - s10);
            float v3 = f0 + fr3 * (f1v - f0);
            float s = a1 * t0[r] + a2 * v2 + a3 * v3;
            t0[r] = 1.f / (1.f + __expf(-s));
            e0 = q00 + fc2 * (q01 - q00); e1 = q10 + fc2 * (q11 - q10);
            v2 = e0 + fr2 * (e1 - e0);
            f0 = s01 + fc3 * (u01 - s01); f1v = s11 + fc3 * (u11 - s11);
            v3 = f0 + fr3 * (f1v - f0);
            s = a1 * t1[r] + a2 * v2 + a3 * v3;
            t1[r] = 1.f / (1.f + __expf(-s));
        }
        // repack S^T frags -> PV A-frag (verified mapping)
        int base0 = ((2 * g) & 3) * 16 + idx;
        int base1 = ((2 * g + 1) & 3) * 16 + idx;
        bool hi = g >= 2;
        s16x8 pa;
#pragma unroll
        for (int r = 0; r < 4; ++r) {
            float v00 = __shfl(t0[r], base0); float v10 = __shfl(t1[r], base0);
            float v01 = __shfl(t0[r], base1); float v11 = __shfl(t1[r], base1);
            pa[r]     = (short)f2b(hi ? v10 : v00);
            pa[4 + r] = (short)f2b(hi ? v11 : v01);
        }
        // PV: acc[cf] += S[16 x 32] * V[32 x 256-cols]
        const ushort_t* vp = V + (size_t)idx * N1 + mm0 + g * 8;
#pragma unroll
        for (int cf = 0; cf < 16; ++cf) {
            s16x8 bv = *reinterpret_cast<const s16x8*>(vp + (size_t)cf * 16 * N1);
            acc[cf] = MFMA16(pa, bv, acc[cf]);
        }
    }

    // ---- cross-wave reduction: (w0+=w2, w1+=w3), (w0+=w1), total -> ps[0] ----
    int lrow = g * 4;
    if (w >= 2) {
#pragma unroll
        for (int cf = 0; cf < 16; ++cf)
#pragma unroll
            for (int q = 0; q < 4; ++q)
                ps[w - 2][lrow + q][cf * 16 + idx] = acc[cf][q];
    }
    __syncthreads();
    if (w < 2) {
#pragma unroll
        for (int cf = 0; cf < 16; ++cf)
#pragma unroll
            for (int q = 0; q < 4; ++q)
                acc[cf][q] += ps[w][lrow + q][cf * 16 + idx];
    }
    __syncthreads();
    if (w == 1) {
#pragma unroll
        for (int cf = 0; cf < 16; ++cf)
#pragma unroll
            for (int q = 0; q < 4; ++q)
                ps[0][lrow + q][cf * 16 + idx] = acc[cf][q];
    }
    __syncthreads();
    if (w == 0) {
#pragma unroll
        for (int cf = 0; cf < 16; ++cf)
#pragma unroll
            for (int q = 0; q < 4; ++q)
                ps[0][lrow + q][cf * 16 + idx] += acc[cf][q];
    }
    __syncthreads();

    // ---- vectorized output write: thread t -> row t>>4, cols (t&15)*16..+16 ----
    int row = threadIdx.x >> 4;
    int c0o = (threadIdx.x & 15) * 16;
    const ushort_t* xrow = X + (size_t)(rowBase + row) * 256 + c0o;
    float* orow = out + ((size_t)b * N1 + rowBase + row) * C1 + c0o;
#pragma unroll
    for (int u = 0; u < 16; u += 4) {
        f32x4 v;
#pragma unroll
        for (int j = 0; j < 4; ++j)
            v[j] = ps[0][row][c0o + u + j] + b2f(xrow[u + j]);
        *reinterpret_cast<f32x4*>(&orow[u]) = v;
    }
}

extern "C" void kernel_launch(void* const* d_in, const int* in_sizes, int n_in,
                              void* d_out, int out_size, void* d_ws, size_t ws_size,
                              hipStream_t stream) {
    const float* f1 = (const float*)d_in[0];
    const float* f2 = (const float*)d_in[1];
    const float* f3 = (const float*)d_in[2];
    const float* w1 = (const float*)d_in[3];
    const float* b1 = (const float*)d_in[4];
    const float* w2 = (const float*)d_in[5];
    const float* b2 = (const float*)d_in[6];
    const float* w3 = (const float*)d_in[7];
    const float* b3 = (const float*)d_in[8];
    const float* a1 = (const float*)d_in[9];
    const float* a2 = (const float*)d_in[10];
    const float* a3 = (const float*)d_in[11];

    char* ws = (char*)d_ws;
    size_t off = 0;
    auto alloc = [&](size_t bytes) -> void* {
        void* p = ws + off;
        off += (bytes + 255) & ~(size_t)255;
        return p;
    };
    ushort_t* w1t = (ushort_t*)alloc((size_t)256 * 256 * 2);
    ushort_t* w2t = (ushort_t*)alloc((size_t)256 * 512 * 2);
    ushort_t* w3t = (ushort_t*)alloc((size_t)256 * 1024 * 2);
    ushort_t* x1b = (ushort_t*)alloc((size_t)BATCH * N1 * C1 * 2);
    ushort_t* x1t = (ushort_t*)alloc((size_t)BATCH * N1 * C1 * 2);
    ushort_t* x2b = (ushort_t*)alloc((size_t)BATCH * N2 * C1 * 2);
    ushort_t* x3b = (ushort_t*)alloc((size_t)BATCH * N3 * C1 * 2);
    float*    att2 = (float*)alloc((size_t)BATCH * N2 * N2 * 4);
    float*    att3 = (float*)alloc((size_t)BATCH * N3 * N3 * 4);

    k_wt<<<(65536 + 131072 + 262144 + 255) / 256, 256, 0, stream>>>(w1, w2, w3, w1t, w2t, w3t);

    k_proj<<<PB3 + PB2 + PB1, 256, 0, stream>>>(f1, f2, f3, w1t, w2t, w3t,
                                                b1, b2, b3, x1b, x1t, x2b, x3b);

    k_xxt<<<16 + 256, 256, 0, stream>>>(x2b, x3b, att2, att3);

    k_attpv<<<1024, 256, 0, stream>>>(x1b, x1t, att2, att3, a1, a2, a3, (float*)d_out);
}

// Round 8
// 213.846 us; speedup vs baseline: 1.3490x; 1.3490x over previous
//
#include <hip/hip_runtime.h>

typedef unsigned short ushort_t;
typedef short s16x8 __attribute__((ext_vector_type(8)));
typedef float f32x4 __attribute__((ext_vector_type(4)));

#define MFMA16(a, b, c) __builtin_amdgcn_mfma_f32_16x16x32_bf16((a), (b), (c), 0, 0, 0)

// ---- sizes ----
#define BATCH 16
#define N1 1024
#define C1 256
#define N2 256
#define N3 64
#define PB3 64
#define PB2 256
#define PB1 256
#define TST 72

static __device__ __forceinline__ ushort_t f2b(float f) {
    unsigned int u = __builtin_bit_cast(unsigned int, f);
    unsigned int r = (u + 0x7fffu + ((u >> 16) & 1u)) >> 16;
    return (ushort_t)r;
}
static __device__ __forceinline__ float b2f(ushort_t b) {
    unsigned int u = ((unsigned int)b) << 16;
    return __builtin_bit_cast(float, u);
}
static __device__ __forceinline__ s16x8 cvt8(const float* p) {
    f32x4 lo = *reinterpret_cast<const f32x4*>(p);
    f32x4 hi = *reinterpret_cast<const f32x4*>(p + 4);
    s16x8 r;
#pragma unroll
    for (int i = 0; i < 4; ++i) {
        r[i]     = (short)f2b(lo[i]);
        r[i + 4] = (short)f2b(hi[i]);
    }
    return r;
}

// ---- async global->LDS stage of a 128 x BK bf16 tile (row-major, stride BK) ----
// 1KB segments; LDS dest = wave-uniform base + lane*16 (HW); per-lane global src.
template <int BK, int NW>
static __device__ __forceinline__ void stage_tile(
    const ushort_t* __restrict__ g, int rowBase, int rowStride, int kOff,
    ushort_t* lds, int w, int l)
{
    constexpr int SEGS = (128 * BK) / 512;   // 1KB segments per tile
    constexpr int PW   = SEGS / NW;          // segments per wave
    constexpr int LPR  = BK / 8;             // lanes per row
    constexpr int RPS  = 512 / BK;           // rows per segment
#pragma unroll
    for (int c = 0; c < PW; ++c) {
        int seg = w * PW + c;
        int row = seg * RPS + l / LPR;
        int col = (l % LPR) * 8;
        const ushort_t* src = g + (size_t)(rowBase + row) * rowStride + kOff + col;
        __builtin_amdgcn_global_load_lds(
            (const __attribute__((address_space(1))) unsigned int*)src,
            (__attribute__((address_space(3))) unsigned int*)(lds + seg * 512),
            16, 0, 0);
    }
}

// ---- merged transpose+convert of weights: wt[d][k] = bf16(w[k][d]) ----
__global__ void k_wt(const float* __restrict__ w1, const float* __restrict__ w2,
                     const float* __restrict__ w3,
                     ushort_t* __restrict__ w1t, ushort_t* __restrict__ w2t,
                     ushort_t* __restrict__ w3t) {
    int i = blockIdx.x * 256 + threadIdx.x;
    if (i < 65536) {
        int d = i >> 8, k = i & 255;
        w1t[i] = f2b(w1[k * 256 + d]);
    } else if (i < 65536 + 131072) {
        int j = i - 65536;
        int d = j >> 9, k = j & 511;
        w2t[j] = f2b(w2[k * 256 + d]);
    } else if (i < 65536 + 131072 + 262144) {
        int j = i - 65536 - 131072;
        int d = j >> 10, k = j & 1023;
        w3t[j] = f2b(w3[k * 256 + d]);
    }
}

template <int K>
static __device__ __forceinline__ void proj16(
    const float* __restrict__ A, const ushort_t* __restrict__ wt,
    const float* __restrict__ bias, ushort_t* __restrict__ xb,
    int tile, int w, int lr, int lk)
{
    int rowBase = tile * 16;
    const float* arow = A + (size_t)(rowBase + lr) * K + lk;
    f32x4 acc[4] = {};
#pragma unroll 4
    for (int kk = 0; kk < K; kk += 32) {
        s16x8 af = cvt8(arow + kk);
#pragma unroll
        for (int t = 0; t < 4; ++t) {
            const ushort_t* bp = wt + (size_t)(w * 64 + t * 16 + lr) * K + kk + lk;
            acc[t] = MFMA16(af, *reinterpret_cast<const s16x8*>(bp), acc[t]);
        }
    }
    int r0 = rowBase + (lk >> 3) * 4;
#pragma unroll
    for (int t = 0; t < 4; ++t) {
        int c = w * 64 + t * 16 + lr;
        float bs = bias[c];
#pragma unroll
        for (int j = 0; j < 4; ++j)
            xb[(size_t)(r0 + j) * 256 + c] = f2b(acc[t][j] + bs);
    }
}

// ---- merged projection GEMM; f1 path does 2-pass LDS transpose for x1t ----
__global__ __launch_bounds__(256) void k_proj(
    const float* __restrict__ f1, const float* __restrict__ f2,
    const float* __restrict__ f3,
    const ushort_t* __restrict__ w1t, const ushort_t* __restrict__ w2t,
    const ushort_t* __restrict__ w3t,
    const float* __restrict__ b1, const float* __restrict__ b2,
    const float* __restrict__ b3,
    ushort_t* __restrict__ x1b, ushort_t* __restrict__ x1t,
    ushort_t* __restrict__ x2b, ushort_t* __restrict__ x3b)
{
    __shared__ ushort_t sT[128 * TST];   // 18.4 KB

    int bid = blockIdx.x;
    int w = threadIdx.x >> 6, l = threadIdx.x & 63;
    int lr = l & 15, g = l >> 4, lk = g * 8;

    if (bid < PB3) {
        proj16<1024>(f3, w3t, b3, x3b, bid, w, lr, lk);
    } else if (bid < PB3 + PB2) {
        proj16<512>(f2, w2t, b2, x2b, bid - PB3, w, lr, lk);
    } else {
        int tile = bid - PB3 - PB2;
        int rowBase = tile * 64;
        const float* arow = f1 + (size_t)(rowBase + w * 16 + lr) * 256 + lk;
        f32x4 acc[16] = {};
#pragma unroll 2
        for (int kk = 0; kk < 256; kk += 32) {
            s16x8 af = cvt8(arow + kk);
#pragma unroll
            for (int t = 0; t < 16; ++t) {
                const ushort_t* bp = w1t + (size_t)(t * 16 + lr) * 256 + kk + lk;
                acc[t] = MFMA16(af, *reinterpret_cast<const s16x8*>(bp), acc[t]);
            }
        }
        int rl0 = w * 16 + g * 4;
        int bIdx = rowBase >> 10, mBase = rowBase & 1023;
#pragma unroll
        for (int p = 0; p < 2; ++p) {
            if (p) __syncthreads();
#pragma unroll
            for (int t = 0; t < 8; ++t) {
                int tt = p * 8 + t;
                int c = tt * 16 + lr;
                float bs = b1[c];
#pragma unroll
                for (int j = 0; j < 4; ++j) {
                    float v = acc[tt][j] + bs;
                    ushort_t bits = f2b(v);
                    x1b[(size_t)(rowBase + rl0 + j) * 256 + c] = bits;
                    sT[(c - p * 128) * TST + rl0 + j] = bits;
                }
            }
            __syncthreads();
            int cl = threadIdx.x >> 1, q = threadIdx.x & 1;
            const uint4* src = reinterpret_cast<const uint4*>(&sT[cl * TST + q * 32]);
            uint4* dst = reinterpret_cast<uint4*>(
                &x1t[(((size_t)bIdx * 256 + p * 128 + cl) << 10) + mBase + q * 32]);
            dst[0] = src[0]; dst[1] = src[1]; dst[2] = src[2]; dst[3] = src[3];
        }
    }
}

// ---- merged Gram matrices ----
__global__ __launch_bounds__(256) void k_xxt(
    const ushort_t* __restrict__ x2b, const ushort_t* __restrict__ x3b,
    float* __restrict__ att2, float* __restrict__ att3)
{
    int bid = blockIdx.x;
    const ushort_t* x; float* att; int n, b, bx, by;
    if (bid < 16) { x = x3b; att = att3; n = 64; b = bid; bx = 0; by = 0; }
    else {
        int j = bid - 16;
        x = x2b; att = att2; n = 256;
        b = j >> 4; bx = (j & 15) & 3; by = (j & 15) >> 2;
    }
    int w = threadIdx.x >> 6, l = threadIdx.x & 63;
    int lr = l & 15, lk = (l >> 4) * 8;
    int rowBase = bx * 64 + (w >> 1) * 32;
    int colBase = by * 64 + (w & 1) * 32;
    const ushort_t* xb = x + (size_t)b * n * 256;

    f32x4 acc[2][2] = {};
#pragma unroll 2
    for (int kk = 0; kk < 256; kk += 32) {
        s16x8 a[2], bb[2];
#pragma unroll
        for (int i = 0; i < 2; ++i)
            a[i] = *reinterpret_cast<const s16x8*>(xb + (size_t)(rowBase + i * 16 + lr) * 256 + kk + lk);
#pragma unroll
        for (int j = 0; j < 2; ++j)
            bb[j] = *reinterpret_cast<const s16x8*>(xb + (size_t)(colBase + j * 16 + lr) * 256 + kk + lk);
#pragma unroll
        for (int i = 0; i < 2; ++i)
#pragma unroll
            for (int j = 0; j < 2; ++j)
                acc[i][j] = MFMA16(a[i], bb[j], acc[i][j]);
    }
    float* ab = att + (size_t)b * n * n;
#pragma unroll
    for (int i = 0; i < 2; ++i)
#pragma unroll
        for (int j = 0; j < 2; ++j)
#pragma unroll
            for (int q = 0; q < 4; ++q) {
                int r = rowBase + i * 16 + (l >> 4) * 4 + q;
                int c = colBase + j * 16 + lr;
                ab[(size_t)r * n + c] = acc[i][j][q];
            }
}

// ---- k_att: LDS-staged GEMM att1 tile + bilinear blend + sigmoid -> attb ----
// 128x128 tile, BK=32, K=256 (8 steps), 4 waves 4x4 frags. XCD-pinned grid.
__global__ __launch_bounds__(256) void k_att(
    const ushort_t* __restrict__ x1b,
    const float* __restrict__ att2, const float* __restrict__ att3,
    const float* __restrict__ a1p, const float* __restrict__ a2p,
    const float* __restrict__ a3p, ushort_t* __restrict__ att)
{
    __shared__ ushort_t As[2][128 * 32];
    __shared__ ushort_t Bs[2][128 * 32];

    int i = blockIdx.x;
    int b = (i & 7) | ((i >> 9) << 3);
    int tile = (i >> 3) & 63;
    int rowT = (tile >> 3) * 128, colT = (tile & 7) * 128;

    int w = threadIdx.x >> 6, l = threadIdx.x & 63;
    int idx = l & 15, g = l >> 4;
    int rowHalf = w >> 1, colHalf = w & 1;

    const ushort_t* X = x1b + (size_t)b * N1 * C1;

    stage_tile<32, 4>(X, rowT, 256, 0, As[0], w, l);
    stage_tile<32, 4>(X, colT, 256, 0, Bs[0], w, l);

    f32x4 acc[4][4] = {};
    for (int t = 0; t < 8; ++t) {
        __syncthreads();
        if (t < 7) {
            stage_tile<32, 4>(X, rowT, 256, (t + 1) * 32, As[(t + 1) & 1], w, l);
            stage_tile<32, 4>(X, colT, 256, (t + 1) * 32, Bs[(t + 1) & 1], w, l);
        }
        const ushort_t* Ab = As[t & 1];
        const ushort_t* Bb = Bs[t & 1];
        s16x8 af[4], bf[4];
#pragma unroll
        for (int ii = 0; ii < 4; ++ii)
            af[ii] = *reinterpret_cast<const s16x8*>(Ab + (rowHalf * 64 + ii * 16 + idx) * 32 + g * 8);
#pragma unroll
        for (int jj = 0; jj < 4; ++jj)
            bf[jj] = *reinterpret_cast<const s16x8*>(Bb + (colHalf * 64 + jj * 16 + idx) * 32 + g * 8);
#pragma unroll
        for (int ii = 0; ii < 4; ++ii)
#pragma unroll
            for (int jj = 0; jj < 4; ++jj)
                acc[ii][jj] = MFMA16(af[ii], bf[jj], acc[ii][jj]);
    }

    float a1 = *a1p, a2 = *a2p, a3 = *a3p;
    const float* A2 = att2 + (size_t)b * N2 * N2;
    const float* A3 = att3 + (size_t)b * N3 * N3;
    ushort_t* ab = att + (size_t)b * N1 * N1;
    int rowW = rowT + rowHalf * 64, colW = colT + colHalf * 64;

#pragma unroll
    for (int ii = 0; ii < 4; ++ii)
#pragma unroll
        for (int jj = 0; jj < 4; ++jj)
#pragma unroll
            for (int q = 0; q < 4; ++q) {
                int nn = rowW + ii * 16 + g * 4 + q;
                int mm = colW + jj * 16 + idx;
                int r2l = nn >> 2, c2l = mm >> 2;
                int r2h = min(r2l + 1, N2 - 1), c2h = min(c2l + 1, N2 - 1);
                float fr2 = (float)(nn & 3) * 0.25f, fc2 = (float)(mm & 3) * 0.25f;
                float v2 =
                    (1.f - fr2) * ((1.f - fc2) * A2[r2l * N2 + c2l] + fc2 * A2[r2l * N2 + c2h]) +
                    fr2 * ((1.f - fc2) * A2[r2h * N2 + c2l] + fc2 * A2[r2h * N2 + c2h]);
                int r3l = nn >> 4, c3l = mm >> 4;
                int r3h = min(r3l + 1, N3 - 1), c3h = min(c3l + 1, N3 - 1);
                float fr3 = (float)(nn & 15) * 0.0625f, fc3 = (float)(mm & 15) * 0.0625f;
                float v3 =
                    (1.f - fr3) * ((1.f - fc3) * A3[r3l * N3 + c3l] + fc3 * A3[r3l * N3 + c3h]) +
                    fr3 * ((1.f - fc3) * A3[r3h * N3 + c3l] + fc3 * A3[r3h * N3 + c3h]);
                float s = a1 * acc[ii][jj][q] + a2 * v2 + a3 * v3;
                float sig = 1.f / (1.f + __expf(-s));
                ab[(size_t)nn * N1 + mm] = f2b(sig);
            }
}

// ---- k_pv: LDS-staged GEMM out = residual + attb @ x1; 128x128 tile, BK=64, 8 waves ----
__global__ __launch_bounds__(512) void k_pv(
    const ushort_t* __restrict__ att, const ushort_t* __restrict__ x1t,
    const ushort_t* __restrict__ x1b, float* __restrict__ out)
{
    __shared__ ushort_t As[2][128 * 64];
    __shared__ ushort_t Bs[2][128 * 64];

    int i = blockIdx.x;
    int b = (i & 7) | (((i >> 7) & 1) << 3);
    int tile = (i >> 3) & 15;
    int rowT = (tile & 7) * 128, colT = (tile >> 3) * 128;

    int w = threadIdx.x >> 6, l = threadIdx.x & 63;
    int idx = l & 15, g = l >> 4;
    int rowHalf = w >> 2;   // 0..1 -> 64 rows
    int colQ = w & 3;       // 0..3 -> 32 cols

    const ushort_t* A = att + (size_t)b * N1 * N1;   // [1024][1024]
    const ushort_t* B = x1t + (size_t)b * C1 * N1;   // [256][1024]

    stage_tile<64, 8>(A, rowT, 1024, 0, As[0], w, l);
    stage_tile<64, 8>(B, colT, 1024, 0, Bs[0], w, l);

    f32x4 acc[4][2] = {};
    for (int t = 0; t < 16; ++t) {
        __syncthreads();
        if (t < 15) {
            stage_tile<64, 8>(A, rowT, 1024, (t + 1) * 64, As[(t + 1) & 1], w, l);
            stage_tile<64, 8>(B, colT, 1024, (t + 1) * 64, Bs[(t + 1) & 1], w, l);
        }
        const ushort_t* Ab = As[t & 1];
        const ushort_t* Bb = Bs[t & 1];
#pragma unroll
        for (int kk = 0; kk < 64; kk += 32) {
            s16x8 af[4], bf[2];
#pragma unroll
            for (int ii = 0; ii < 4; ++ii)
                af[ii] = *reinterpret_cast<const s16x8*>(Ab + (rowHalf * 64 + ii * 16 + idx) * 64 + kk + g * 8);
#pragma unroll
            for (int jj = 0; jj < 2; ++jj)
                bf[jj] = *reinterpret_cast<const s16x8*>(Bb + (colQ * 32 + jj * 16 + idx) * 64 + kk + g * 8);
#pragma unroll
            for (int ii = 0; ii < 4; ++ii)
#pragma unroll
                for (int jj = 0; jj < 2; ++jj)
                    acc[ii][jj] = MFMA16(af[ii], bf[jj], acc[ii][jj]);
        }
    }
    int rowW = rowT + rowHalf * 64, colW = colT + colQ * 32;
#pragma unroll
    for (int ii = 0; ii < 4; ++ii)
#pragma unroll
        for (int jj = 0; jj < 2; ++jj)
#pragma unroll
            for (int q = 0; q < 4; ++q) {
                int r = rowW + ii * 16 + g * 4 + q;
                int c = colW + jj * 16 + idx;
                size_t o = ((size_t)b * N1 + r) * C1 + c;
                out[o] = b2f(x1b[(size_t)b * N1 * C1 + (size_t)r * 256 + c]) + acc[ii][jj][q];
            }
}

extern "C" void kernel_launch(void* const* d_in, const int* in_sizes, int n_in,
                              void* d_out, int out_size, void* d_ws, size_t ws_size,
                              hipStream_t stream) {
    const float* f1 = (const float*)d_in[0];
    const float* f2 = (const float*)d_in[1];
    const float* f3 = (const float*)d_in[2];
    const float* w1 = (const float*)d_in[3];
    const float* b1 = (const float*)d_in[4];
    const float* w2 = (const float*)d_in[5];
    const float* b2 = (const float*)d_in[6];
    const float* w3 = (const float*)d_in[7];
    const float* b3 = (const float*)d_in[8];
    const float* a1 = (const float*)d_in[9];
    const float* a2 = (const float*)d_in[10];
    const float* a3 = (const float*)d_in[11];

    char* ws = (char*)d_ws;
    size_t off = 0;
    auto alloc = [&](size_t bytes) -> void* {
        void* p = ws + off;
        off += (bytes + 255) & ~(size_t)255;
        return p;
    };
    ushort_t* w1t = (ushort_t*)alloc((size_t)256 * 256 * 2);
    ushort_t* w2t = (ushort_t*)alloc((size_t)256 * 512 * 2);
    ushort_t* w3t = (ushort_t*)alloc((size_t)256 * 1024 * 2);
    ushort_t* x1b = (ushort_t*)alloc((size_t)BATCH * N1 * C1 * 2);
    ushort_t* x1t = (ushort_t*)alloc((size_t)BATCH * N1 * C1 * 2);
    ushort_t* x2b = (ushort_t*)alloc((size_t)BATCH * N2 * C1 * 2);
    ushort_t* x3b = (ushort_t*)alloc((size_t)BATCH * N3 * C1 * 2);
    float*    att2 = (float*)alloc((size_t)BATCH * N2 * N2 * 4);
    float*    att3 = (float*)alloc((size_t)BATCH * N3 * N3 * 4);
    ushort_t* attb = (ushort_t*)alloc((size_t)BATCH * N1 * N1 * 2);

    k_wt<<<(65536 + 131072 + 262144 + 255) / 256, 256, 0, stream>>>(w1, w2, w3, w1t, w2t, w3t);

    k_proj<<<PB3 + PB2 + PB1, 256, 0, stream>>>(f1, f2, f3, w1t, w2t, w3t,
                                                b1, b2, b3, x1b, x1t, x2b, x3b);

    k_xxt<<<16 + 256, 256, 0, stream>>>(x2b, x3b, att2, att3);

    k_att<<<1024, 256, 0, stream>>>(x1b, att2, att3, a1, a2, a3, attb);

    k_pv<<<256, 512, 0, stream>>>(attb, x1t, x1b, (float*)d_out);
}

// Round 9
// 204.321 us; speedup vs baseline: 1.4119x; 1.0466x over previous
//
#include <hip/hip_runtime.h>

typedef unsigned short ushort_t;
typedef short s16x8 __attribute__((ext_vector_type(8)));
typedef float f32x4 __attribute__((ext_vector_type(4)));

#define MFMA16(a, b, c) __builtin_amdgcn_mfma_f32_16x16x32_bf16((a), (b), (c), 0, 0, 0)

// ---- sizes ----
#define BATCH 16
#define N1 1024
#define C1 256
#define N2 256
#define N3 64
// proj block counts (all 16-row x 256-col tiles, split-K over 4 waves)
#define QB3 64
#define QB2 256
#define QB1 1024
// partial-sum LDS row stride (floats)
#define PSS 260

static __device__ __forceinline__ ushort_t f2b(float f) {
    unsigned int u = __builtin_bit_cast(unsigned int, f);
    unsigned int r = (u + 0x7fffu + ((u >> 16) & 1u)) >> 16;
    return (ushort_t)r;
}
static __device__ __forceinline__ float b2f(ushort_t b) {
    unsigned int u = ((unsigned int)b) << 16;
    return __builtin_bit_cast(float, u);
}
static __device__ __forceinline__ s16x8 cvt8(const float* p) {
    f32x4 lo = *reinterpret_cast<const f32x4*>(p);
    f32x4 hi = *reinterpret_cast<const f32x4*>(p + 4);
    s16x8 r;
#pragma unroll
    for (int i = 0; i < 4; ++i) {
        r[i]     = (short)f2b(lo[i]);
        r[i + 4] = (short)f2b(hi[i]);
    }
    return r;
}

// ---- async global->LDS stage of a 128 x BK bf16 tile (row-major, stride BK) ----
template <int BK, int NW>
static __device__ __forceinline__ void stage_tile(
    const ushort_t* __restrict__ g, int rowBase, int rowStride, int kOff,
    ushort_t* lds, int w, int l)
{
    constexpr int SEGS = (128 * BK) / 512;
    constexpr int PW   = SEGS / NW;
    constexpr int LPR  = BK / 8;
    constexpr int RPS  = 512 / BK;
#pragma unroll
    for (int c = 0; c < PW; ++c) {
        int seg = w * PW + c;
        int row = seg * RPS + l / LPR;
        int col = (l % LPR) * 8;
        const ushort_t* src = g + (size_t)(rowBase + row) * rowStride + kOff + col;
        __builtin_amdgcn_global_load_lds(
            (const __attribute__((address_space(1))) unsigned int*)src,
            (__attribute__((address_space(3))) unsigned int*)(lds + seg * 512),
            16, 0, 0);
    }
}

// ---- tiled weight transpose: wt[d][k] = bf16(w[k][d]); 64x64 tiles via LDS ----
__global__ __launch_bounds__(256) void k_wt(
    const float* __restrict__ w1, const float* __restrict__ w2,
    const float* __restrict__ w3,
    ushort_t* __restrict__ w1t, ushort_t* __restrict__ w2t,
    ushort_t* __restrict__ w3t)
{
    __shared__ float sA[64][65];   // 16.6 KB

    int bid = blockIdx.x;
    const float* w; ushort_t* wt; int K, ktile, dtile;
    if (bid < 16)      { w = w1; wt = w1t; K = 256;  int j = bid;      ktile = j >> 2; dtile = j & 3; }
    else if (bid < 48) { w = w2; wt = w2t; K = 512;  int j = bid - 16; ktile = j >> 2; dtile = j & 3; }
    else               { w = w3; wt = w3t; K = 1024; int j = bid - 48; ktile = j >> 2; dtile = j & 3; }
    int k0 = ktile * 64, d0 = dtile * 64;

    // read: 4 lanes per k-row, 16 floats each (coalesced 256B per row)
    int jr = threadIdx.x >> 2, ch = (threadIdx.x & 3) * 16;
    const float* src = w + (size_t)(k0 + jr) * 256 + d0 + ch;
#pragma unroll
    for (int i = 0; i < 16; i += 4)
        *reinterpret_cast<f32x4*>(&sA[jr][ch + i]) = *reinterpret_cast<const f32x4*>(&src[i]);
    __syncthreads();
    // write: 4 lanes per d-row, 16 k each (32B vector stores)
    int jd = threadIdx.x >> 2, kc = (threadIdx.x & 3) * 16;
    ushort_t ob[16];
#pragma unroll
    for (int i = 0; i < 16; ++i) ob[i] = f2b(sA[kc + i][jd]);
    uint4* dst = reinterpret_cast<uint4*>(&wt[(size_t)(d0 + jd) * K + k0 + kc]);
    dst[0] = *reinterpret_cast<uint4*>(&ob[0]);
    dst[1] = *reinterpret_cast<uint4*>(&ob[8]);
}

// ---- projection tile: 16 rows x 256 cols; 4 waves split K; LDS reduce; coop epilogue ----
template <int K>
static __device__ __forceinline__ void projSplitK(
    const float* __restrict__ A, const ushort_t* __restrict__ wt,
    const float* __restrict__ bias, ushort_t* __restrict__ xb,
    ushort_t* __restrict__ x1t, int tile, int tid,
    float* __restrict__ ps0, float* __restrict__ ps1)
{
    int w = tid >> 6, l = tid & 63;
    int lr = l & 15, g = l >> 4, lk = g * 8;
    int rowBase = tile * 16;
    constexpr int KW = K / 4;
    int kbeg = w * KW;

    const float* arow = A + (size_t)(rowBase + lr) * K + kbeg + lk;
    f32x4 acc[16] = {};
#pragma unroll
    for (int kk = 0; kk < KW; kk += 32) {
        s16x8 af = cvt8(arow + kk);
#pragma unroll
        for (int t = 0; t < 16; ++t) {
            const ushort_t* bp = wt + (size_t)(t * 16 + lr) * K + kbeg + kk + lk;
            acc[t] = MFMA16(af, *reinterpret_cast<const s16x8*>(bp), acc[t]);
        }
    }
    // pairwise reduction into ps0
    if (w >= 2) {
        float* dst = (w == 2) ? ps0 : ps1;
#pragma unroll
        for (int t = 0; t < 16; ++t)
#pragma unroll
            for (int q = 0; q < 4; ++q)
                dst[(g * 4 + q) * PSS + t * 16 + lr] = acc[t][q];
    }
    __syncthreads();
    if (w < 2) {
        float* src = (w == 0) ? ps0 : ps1;
#pragma unroll
        for (int t = 0; t < 16; ++t)
#pragma unroll
            for (int q = 0; q < 4; ++q)
                acc[t][q] += src[(g * 4 + q) * PSS + t * 16 + lr];
    }
    __syncthreads();
    if (w == 1) {
#pragma unroll
        for (int t = 0; t < 16; ++t)
#pragma unroll
            for (int q = 0; q < 4; ++q)
                ps0[(g * 4 + q) * PSS + t * 16 + lr] = acc[t][q];
    }
    __syncthreads();
    if (w == 0) {
#pragma unroll
        for (int t = 0; t < 16; ++t)
#pragma unroll
            for (int q = 0; q < 4; ++q)
                ps0[(g * 4 + q) * PSS + t * 16 + lr] += acc[t][q];
    }
    __syncthreads();

    // cooperative x-write: thread -> row tid>>4, cols (tid&15)*16..+16
    {
        int j = tid >> 4, c0 = (tid & 15) * 16;
        ushort_t ob[16];
#pragma unroll
        for (int u = 0; u < 16; ++u)
            ob[u] = f2b(ps0[j * PSS + c0 + u] + bias[c0 + u]);
        uint4* dst = reinterpret_cast<uint4*>(&xb[(size_t)(rowBase + j) * 256 + c0]);
        dst[0] = *reinterpret_cast<uint4*>(&ob[0]);
        dst[1] = *reinterpret_cast<uint4*>(&ob[8]);
    }
    // f1 only: transposed write x1t[b][c][m], thread -> col tid, 16 m's (32B)
    if (x1t) {
        int c = tid;
        int bI = rowBase >> 10, mBase = rowBase & 1023;
        float bs = bias[c];
        ushort_t ob[16];
#pragma unroll
        for (int j = 0; j < 16; ++j)
            ob[j] = f2b(ps0[j * PSS + c] + bs);
        uint4* dst = reinterpret_cast<uint4*>(&x1t[(((size_t)bI * 256 + c) << 10) + mBase]);
        dst[0] = *reinterpret_cast<uint4*>(&ob[0]);
        dst[1] = *reinterpret_cast<uint4*>(&ob[8]);
    }
}

__global__ __launch_bounds__(256) void k_proj(
    const float* __restrict__ f1, const float* __restrict__ f2,
    const float* __restrict__ f3,
    const ushort_t* __restrict__ w1t, const ushort_t* __restrict__ w2t,
    const ushort_t* __restrict__ w3t,
    const float* __restrict__ b1, const float* __restrict__ b2,
    const float* __restrict__ b3,
    ushort_t* __restrict__ x1b, ushort_t* __restrict__ x1t,
    ushort_t* __restrict__ x2b, ushort_t* __restrict__ x3b)
{
    __shared__ float ps[2][16 * PSS];   // 33.3 KB

    int bid = blockIdx.x;
    if (bid < QB3)
        projSplitK<1024>(f3, w3t, b3, x3b, nullptr, bid, threadIdx.x, ps[0], ps[1]);
    else if (bid < QB3 + QB2)
        projSplitK<512>(f2, w2t, b2, x2b, nullptr, bid - QB3, threadIdx.x, ps[0], ps[1]);
    else
        projSplitK<256>(f1, w1t, b1, x1b, x1t, bid - QB3 - QB2, threadIdx.x, ps[0], ps[1]);
}

// ---- merged Gram matrices ----
__global__ __launch_bounds__(256) void k_xxt(
    const ushort_t* __restrict__ x2b, const ushort_t* __restrict__ x3b,
    float* __restrict__ att2, float* __restrict__ att3)
{
    int bid = blockIdx.x;
    const ushort_t* x; float* att; int n, b, bx, by;
    if (bid < 16) { x = x3b; att = att3; n = 64; b = bid; bx = 0; by = 0; }
    else {
        int j = bid - 16;
        x = x2b; att = att2; n = 256;
        b = j >> 4; bx = (j & 15) & 3; by = (j & 15) >> 2;
    }
    int w = threadIdx.x >> 6, l = threadIdx.x & 63;
    int lr = l & 15, lk = (l >> 4) * 8;
    int rowBase = bx * 64 + (w >> 1) * 32;
    int colBase = by * 64 + (w & 1) * 32;
    const ushort_t* xb = x + (size_t)b * n * 256;

    f32x4 acc[2][2] = {};
#pragma unroll 2
    for (int kk = 0; kk < 256; kk += 32) {
        s16x8 a[2], bb[2];
#pragma unroll
        for (int i = 0; i < 2; ++i)
            a[i] = *reinterpret_cast<const s16x8*>(xb + (size_t)(rowBase + i * 16 + lr) * 256 + kk + lk);
#pragma unroll
        for (int j = 0; j < 2; ++j)
            bb[j] = *reinterpret_cast<const s16x8*>(xb + (size_t)(colBase + j * 16 + lr) * 256 + kk + lk);
#pragma unroll
        for (int i = 0; i < 2; ++i)
#pragma unroll
            for (int j = 0; j < 2; ++j)
                acc[i][j] = MFMA16(a[i], bb[j], acc[i][j]);
    }
    float* ab = att + (size_t)b * n * n;
#pragma unroll
    for (int i = 0; i < 2; ++i)
#pragma unroll
        for (int j = 0; j < 2; ++j)
#pragma unroll
            for (int q = 0; q < 4; ++q) {
                int r = rowBase + i * 16 + (l >> 4) * 4 + q;
                int c = colBase + j * 16 + lr;
                ab[(size_t)r * n + c] = acc[i][j][q];
            }
}

// ---- k_att: LDS-staged GEMM + LDS-patch bilinear + sigmoid -> attb ----
__global__ __launch_bounds__(256) void k_att(
    const ushort_t* __restrict__ x1b,
    const float* __restrict__ att2, const float* __restrict__ att3,
    const float* __restrict__ a1p, const float* __restrict__ a2p,
    const float* __restrict__ a3p, ushort_t* __restrict__ att)
{
    __shared__ ushort_t As[2][128 * 32];
    __shared__ ushort_t Bs[2][128 * 32];

    int i = blockIdx.x;
    int b = (i & 7) | ((i >> 9) << 3);
    int tile = (i >> 3) & 63;
    int rowT = (tile >> 3) * 128, colT = (tile & 7) * 128;

    int w = threadIdx.x >> 6, l = threadIdx.x & 63;
    int idx = l & 15, g = l >> 4;
    int rowHalf = w >> 1, colHalf = w & 1;

    const ushort_t* X = x1b + (size_t)b * N1 * C1;
    const float* A2 = att2 + (size_t)b * N2 * N2;
    const float* A3 = att3 + (size_t)b * N3 * N3;

    stage_tile<32, 4>(X, rowT, 256, 0, As[0], w, l);
    stage_tile<32, 4>(X, colT, 256, 0, Bs[0], w, l);

    f32x4 acc[4][4] = {};
    for (int t = 0; t < 8; ++t) {
        __syncthreads();
        if (t < 7) {
            stage_tile<32, 4>(X, rowT, 256, (t + 1) * 32, As[(t + 1) & 1], w, l);
            stage_tile<32, 4>(X, colT, 256, (t + 1) * 32, Bs[(t + 1) & 1], w, l);
        }
        const ushort_t* Ab = As[t & 1];
        const ushort_t* Bb = Bs[t & 1];
        s16x8 af[4], bf[4];
#pragma unroll
        for (int ii = 0; ii < 4; ++ii)
            af[ii] = *reinterpret_cast<const s16x8*>(Ab + (rowHalf * 64 + ii * 16 + idx) * 32 + g * 8);
#pragma unroll
        for (int jj = 0; jj < 4; ++jj)
            bf[jj] = *reinterpret_cast<const s16x8*>(Bb + (colHalf * 64 + jj * 16 + idx) * 32 + g * 8);
#pragma unroll
        for (int ii = 0; ii < 4; ++ii)
#pragma unroll
            for (int jj = 0; jj < 4; ++jj)
                acc[ii][jj] = MFMA16(af[ii], bf[jj], acc[ii][jj]);
    }

    // stage clamped bilinear tap patches into LDS (reuse As/Bs)
    __syncthreads();
    float* patch2 = reinterpret_cast<float*>(&As[0][0]);   // [33][36]
    float* patch3 = reinterpret_cast<float*>(&Bs[0][0]);   // [9][12]
    int r2b = rowT >> 2, c2b = colT >> 2;
    for (int id = threadIdx.x; id < 33 * 33; id += 256) {
        int r = id / 33, c = id - r * 33;
        patch2[r * 36 + c] = A2[min(r2b + r, N2 - 1) * N2 + min(c2b + c, N2 - 1)];
    }
    int r3b = rowT >> 4, c3b = colT >> 4;
    if (threadIdx.x < 81) {
        int r = threadIdx.x / 9, c = threadIdx.x - r * 9;
        patch3[r * 12 + c] = A3[min(r3b + r, N3 - 1) * N3 + min(c3b + c, N3 - 1)];
    }
    __syncthreads();

    float a1 = *a1p, a2 = *a2p, a3 = *a3p;
    ushort_t* ab = att + (size_t)b * N1 * N1;
    int rowW = rowT + rowHalf * 64, colW = colT + colHalf * 64;

#pragma unroll
    for (int ii = 0; ii < 4; ++ii)
#pragma unroll
        for (int jj = 0; jj < 4; ++jj)
#pragma unroll
            for (int q = 0; q < 4; ++q) {
                int nn = rowW + ii * 16 + g * 4 + q;
                int mm = colW + jj * 16 + idx;
                int rr = (nn - rowT) >> 2, cc = (mm - colT) >> 2;
                float fr2 = (float)(nn & 3) * 0.25f, fc2 = (float)(mm & 3) * 0.25f;
                float p00 = patch2[rr * 36 + cc],       p01 = patch2[rr * 36 + cc + 1];
                float p10 = patch2[(rr + 1) * 36 + cc], p11 = patch2[(rr + 1) * 36 + cc + 1];
                float e0 = p00 + fc2 * (p01 - p00), e1 = p10 + fc2 * (p11 - p10);
                float v2 = e0 + fr2 * (e1 - e0);
                int r3 = (nn - rowT) >> 4, c3 = (mm - colT) >> 4;
                float fr3 = (float)(nn & 15) * 0.0625f, fc3 = (float)(mm & 15) * 0.0625f;
                float s00 = patch3[r3 * 12 + c3],       s01 = patch3[r3 * 12 + c3 + 1];
                float s10 = patch3[(r3 + 1) * 12 + c3], s11 = patch3[(r3 + 1) * 12 + c3 + 1];
                float f0 = s00 + fc3 * (s01 - s00), f1v = s10 + fc3 * (s11 - s10);
                float v3 = f0 + fr3 * (f1v - f0);
                float s = a1 * acc[ii][jj][q] + a2 * v2 + a3 * v3;
                float sig = 1.f / (1.f + __expf(-s));
                ab[(size_t)nn * N1 + mm] = f2b(sig);
            }
}

// ---- k_pv: LDS-staged GEMM out = residual + attb @ x1 ----
__global__ __launch_bounds__(512) void k_pv(
    const ushort_t* __restrict__ att, const ushort_t* __restrict__ x1t,
    const ushort_t* __restrict__ x1b, float* __restrict__ out)
{
    __shared__ ushort_t As[2][128 * 64];
    __shared__ ushort_t Bs[2][128 * 64];

    int i = blockIdx.x;
    int b = (i & 7) | (((i >> 7) & 1) << 3);
    int tile = (i >> 3) & 15;
    int rowT = (tile & 7) * 128, colT = (tile >> 3) * 128;

    int w = threadIdx.x >> 6, l = threadIdx.x & 63;
    int idx = l & 15, g = l >> 4;
    int rowHalf = w >> 2;
    int colQ = w & 3;

    const ushort_t* A = att + (size_t)b * N1 * N1;
    const ushort_t* B = x1t + (size_t)b * C1 * N1;

    stage_tile<64, 8>(A, rowT, 1024, 0, As[0], w, l);
    stage_tile<64, 8>(B, colT, 1024, 0, Bs[0], w, l);

    f32x4 acc[4][2] = {};
    for (int t = 0; t < 16; ++t) {
        __syncthreads();
        if (t < 15) {
            stage_tile<64, 8>(A, rowT, 1024, (t + 1) * 64, As[(t + 1) & 1], w, l);
            stage_tile<64, 8>(B, colT, 1024, (t + 1) * 64, Bs[(t + 1) & 1], w, l);
        }
        const ushort_t* Ab = As[t & 1];
        const ushort_t* Bb = Bs[t & 1];
#pragma unroll
        for (int kk = 0; kk < 64; kk += 32) {
            s16x8 af[4], bf[2];
#pragma unroll
            for (int ii = 0; ii < 4; ++ii)
                af[ii] = *reinterpret_cast<const s16x8*>(Ab + (rowHalf * 64 + ii * 16 + idx) * 64 + kk + g * 8);
#pragma unroll
            for (int jj = 0; jj < 2; ++jj)
                bf[jj] = *reinterpret_cast<const s16x8*>(Bb + (colQ * 32 + jj * 16 + idx) * 64 + kk + g * 8);
#pragma unroll
            for (int ii = 0; ii < 4; ++ii)
#pragma unroll
                for (int jj = 0; jj < 2; ++jj)
                    acc[ii][jj] = MFMA16(af[ii], bf[jj], acc[ii][jj]);
        }
    }
    int rowW = rowT + rowHalf * 64, colW = colT + colQ * 32;
#pragma unroll
    for (int ii = 0; ii < 4; ++ii)
#pragma unroll
        for (int jj = 0; jj < 2; ++jj)
#pragma unroll
            for (int q = 0; q < 4; ++q) {
                int r = rowW + ii * 16 + g * 4 + q;
                int c = colW + jj * 16 + idx;
                size_t o = ((size_t)b * N1 + r) * C1 + c;
                out[o] = b2f(x1b[(size_t)b * N1 * C1 + (size_t)r * 256 + c]) + acc[ii][jj][q];
            }
}

extern "C" void kernel_launch(void* const* d_in, const int* in_sizes, int n_in,
                              void* d_out, int out_size, void* d_ws, size_t ws_size,
                              hipStream_t stream) {
    const float* f1 = (const float*)d_in[0];
    const float* f2 = (const float*)d_in[1];
    const float* f3 = (const float*)d_in[2];
    const float* w1 = (const float*)d_in[3];
    const float* b1 = (const float*)d_in[4];
    const float* w2 = (const float*)d_in[5];
    const float* b2 = (const float*)d_in[6];
    const float* w3 = (const float*)d_in[7];
    const float* b3 = (const float*)d_in[8];
    const float* a1 = (const float*)d_in[9];
    const float* a2 = (const float*)d_in[10];
    const float* a3 = (const float*)d_in[11];

    char* ws = (char*)d_ws;
    size_t off = 0;
    auto alloc = [&](size_t bytes) -> void* {
        void* p = ws + off;
        off += (bytes + 255) & ~(size_t)255;
        return p;
    };
    ushort_t* w1t = (ushort_t*)alloc((size_t)256 * 256 * 2);
    ushort_t* w2t = (ushort_t*)alloc((size_t)256 * 512 * 2);
    ushort_t* w3t = (ushort_t*)alloc((size_t)256 * 1024 * 2);
    ushort_t* x1b = (ushort_t*)alloc((size_t)BATCH * N1 * C1 * 2);
    ushort_t* x1t = (ushort_t*)alloc((size_t)BATCH * N1 * C1 * 2);
    ushort_t* x2b = (ushort_t*)alloc((size_t)BATCH * N2 * C1 * 2);
    ushort_t* x3b = (ushort_t*)alloc((size_t)BATCH * N3 * C1 * 2);
    float*    att2 = (float*)alloc((size_t)BATCH * N2 * N2 * 4);
    float*    att3 = (float*)alloc((size_t)BATCH * N3 * N3 * 4);
    ushort_t* attb = (ushort_t*)alloc((size_t)BATCH * N1 * N1 * 2);

    k_wt<<<112, 256, 0, stream>>>(w1, w2, w3, w1t, w2t, w3t);

    k_proj<<<QB3 + QB2 + QB1, 256, 0, stream>>>(f1, f2, f3, w1t, w2t, w3t,
                                                b1, b2, b3, x1b, x1t, x2b, x3b);

    k_xxt<<<16 + 256, 256, 0, stream>>>(x2b, x3b, att2, att3);

    k_att<<<1024, 256, 0, stream>>>(x1b, att2, att3, a1, a2, a3, attb);

    k_pv<<<256, 512, 0, stream>>>(attb, x1t, x1b, (float*)d_out);
}